// Round 1
// 133.031 us; speedup vs baseline: 1.0009x; 1.0009x over previous
//
#include <hip/hip_runtime.h>

typedef unsigned short u16;
typedef __attribute__((ext_vector_type(8))) short short8;
typedef __attribute__((ext_vector_type(4))) float f32x4;

#define X0    (-6.0f)
#define GH    (12.0f / 256.0f)     // grid spacing h = 0.046875
#define LOG2E 1.44269504089f

// gfx950 hardware packed f32->bf16 (RNE), no builtin -- inline asm per guide T12.
__device__ __forceinline__ unsigned int cvtpk(float lo, float hi) {
    unsigned int r;
    asm("v_cvt_pk_bf16_f32 %0, %1, %2" : "=v"(r) : "v"(lo), "v"(hi));
    return r;
}
__device__ __forceinline__ uint4 cvt8u(float4 lo, float4 hi) {
    return make_uint4(cvtpk(lo.x, lo.y), cvtpk(lo.z, lo.w),
                      cvtpk(hi.x, hi.y), cvtpk(hi.z, hi.w));
}
__device__ __forceinline__ void glds16(const float* g, const float* l) {
    __builtin_amdgcn_global_load_lds(
        (const __attribute__((address_space(1))) void*)g,
        (__attribute__((address_space(3))) void*)l, 16, 0, 0);
}

// K1: Hpart[b][ks][v][j] = sum_{s in chunk} value[v][s] * W_cic[s][j].
// M=32 v-rows/block, N=256 j, K-chunk=512 s.
// NEW: full 64 KB A-tile prefetched with 16 glds16 in flight -> ONE barrier,
// then 16 barrier-free MFMA steps (same structure as K3). LDS layout
// [kk][32][32] keeps each glds16's 64 lanes on a contiguous 1 KB run.
__global__ __launch_bounds__(256) void hpart_kernel(
    const float* __restrict__ key, const float* __restrict__ value,
    float* __restrict__ Hpart)
{
    __shared__ float  Vt[16 * 1024];   // 64 KB, [kk][row][32 f32], chunk-swizzled
    __shared__ float2 jf[512];         // 4 KB: (float)j , frac

    const int tid   = threadIdx.x;
    const int v0    = blockIdx.x << 5;    // 0..480
    const int b     = blockIdx.y;
    const int ks    = blockIdx.z;
    const int kbase = ks << 9;            // 512-wide s chunk
    const int lane  = tid & 63;
    const int wave  = tid >> 6;
    const int wj    = wave << 6;          // wave owns 64 j
    const int m15   = lane & 15;
    const int kq    = lane >> 4;

    #pragma unroll
    for (int r = 0; r < 2; ++r) {
        int s = tid + (r << 8);
        float k = key[b * 4096 + kbase + s];
        float u = (k - X0) * (256.0f / 12.0f);
        int j = (int)floorf(u);
        j = j < 0 ? 0 : (j > 254 ? 254 : j);
        float f = u - (float)j;
        f = f < 0.0f ? 0.0f : (f > 1.0f ? 1.0f : f);
        jf[s] = make_float2((float)j, f);
    }

    // issue ALL 16 tile-loads (16B swizzle on the global source, LDS linear)
    const int srow = tid >> 3;                   // 0..31
    const int scs  = (tid & 7) ^ (srow & 7);     // swizzled 16B chunk
    const float* gsrc = value + (size_t)(b * 512 + v0 + srow) * 4096 + kbase
                              + (scs << 2);
    const float* ldst = Vt + (srow << 5) + ((tid & 7) << 2);
    #pragma unroll
    for (int kk = 0; kk < 16; ++kk)
        glds16(gsrc + (kk << 5), ldst + (kk << 10));

    f32x4 acc[2][4];
    #pragma unroll
    for (int i = 0; i < 2; ++i)
        #pragma unroll
        for (int j = 0; j < 4; ++j)
            acc[i][j] = (f32x4){0.f, 0.f, 0.f, 0.f};

    __syncthreads();     // drains all 16 glds + LUT writes; only barrier in K1

    for (int kk = 0; kk < 16; ++kk) {
        const float* Vk = Vt + (kk << 10);

        union U { short8 s; uint4 u; } af[2];
        #pragma unroll
        for (int mi = 0; mi < 2; ++mi) {
            int m  = mi * 16 + m15;
            int c0 = ((2 * kq)     ^ (m & 7)) << 2;
            int c1 = ((2 * kq + 1) ^ (m & 7)) << 2;
            float4 lo = *(const float4*)(Vk + (m << 5) + c0);
            float4 hi = *(const float4*)(Vk + (m << 5) + c1);
            af[mi].u = cvt8u(lo, hi);
        }

        float js[8], fs[8], os[8];
        #pragma unroll
        for (int i = 0; i < 8; ++i) {
            float2 p = jf[(kk << 5) + (kq << 3) + i];
            js[i] = p.x; fs[i] = p.y; os[i] = 1.0f - p.y;
        }
        #pragma unroll
        for (int ni = 0; ni < 4; ++ni) {
            const float J = (float)(wj + ni * 16 + m15);
            float w[8];
            #pragma unroll
            for (int i = 0; i < 8; ++i)
                w[i] = (js[i] == J) ? os[i]
                     : ((js[i] + 1.0f == J) ? fs[i] : 0.0f);
            union U bf;
            bf.u = cvt8u(make_float4(w[0], w[1], w[2], w[3]),
                         make_float4(w[4], w[5], w[6], w[7]));
            #pragma unroll
            for (int mi = 0; mi < 2; ++mi)
                acc[mi][ni] = __builtin_amdgcn_mfma_f32_16x16x32_bf16(
                    af[mi].s, bf.s, acc[mi][ni], 0, 0, 0);
        }
    }

    // private-plane epilogue: plain stores, no atomics
    #pragma unroll
    for (int mi = 0; mi < 2; ++mi)
        #pragma unroll
        for (int ni = 0; ni < 4; ++ni) {
            #pragma unroll
            for (int r = 0; r < 4; ++r) {
                int v = v0 + mi * 16 + (kq << 2) + r;      // row = quad*4+reg
                Hpart[((size_t)(b * 8 + ks) * 512 + v) * 256
                      + wj + ni * 16 + m15] = acc[mi][ni][r];
            }
        }
}

// K2: Hbf[b][v][j] = bf16( sum_{ks<8} Hpart[b][ks][v][j] ). Streaming.
__global__ __launch_bounds__(256) void hred_kernel(
    const float* __restrict__ Hpart, u16* __restrict__ Hbf)
{
    const int gid  = blockIdx.x * 256 + threadIdx.x;   // 0..65535
    const int b    = gid >> 14;
    const size_t off8 = (size_t)(gid & 16383) * 8;
    float4 s0 = make_float4(0.f, 0.f, 0.f, 0.f);
    float4 s1 = make_float4(0.f, 0.f, 0.f, 0.f);
    #pragma unroll
    for (int ks = 0; ks < 8; ++ks) {
        const float* p = Hpart + (size_t)(b * 8 + ks) * 131072 + off8;
        float4 a = *(const float4*)p;
        float4 c = *(const float4*)(p + 4);
        s0.x += a.x; s0.y += a.y; s0.z += a.z; s0.w += a.w;
        s1.x += c.x; s1.y += c.y; s1.z += c.z; s1.w += c.w;
    }
    *(uint4*)(Hbf + (size_t)b * 131072 + off8) = cvt8u(s0, s1);
}

// K3: out[b][t][v] = sum_k G(q_t, x_k) * H[v][k].
// Whole H-tile (128 v x 256 k bf16) staged ONCE -> single barrier, then
// 8 barrier-free MFMA steps with on-the-fly Gaussian B-fragments.
// NEW: Gaussian fragments packed via v_cvt_pk_bf16_f32 (1 inst / bf16 pair).
__global__ __launch_bounds__(256) void gemm_kernel(
    const float* __restrict__ query, const float* __restrict__ log_scale,
    const u16* __restrict__ Hbf, float* __restrict__ out)
{
    extern __shared__ u16 Hl[];        // 128 rows x 264 stride = 67584 B

    const int tid  = threadIdx.x;
    const int v0   = blockIdx.x << 7;
    const int t0   = blockIdx.y << 7;
    const int b    = blockIdx.z;
    const int lane = tid & 63;
    const int wave = tid >> 6;
    const int wv   = (wave & 1) << 6;
    const int wt   = (wave >> 1) << 6;
    const int m15  = lane & 15;
    const int kq   = lane >> 4;

    const float c2 = -0.5f * LOG2E * exp2f(-2.0f * LOG2E * log_scale[0]);
    float q[4];
    for (int ni = 0; ni < 4; ++ni)
        q[ni] = query[b * 4096 + t0 + wt + ni * 16 + m15];

    // stage: thread = (row = tid>>1, half = tid&1); contiguous 256 B per thread
    {
        const int row = tid >> 1, half = tid & 1;
        const u16* src = Hbf + (size_t)(b * 512 + v0 + row) * 256 + half * 128;
        u16* dst = Hl + row * 264 + half * 128;
        #pragma unroll
        for (int i = 0; i < 16; ++i)
            *(uint4*)(dst + i * 8) = *(const uint4*)(src + i * 8);
    }
    __syncthreads();

    f32x4 acc[4][4];
    for (int i = 0; i < 4; ++i)
        for (int j = 0; j < 4; ++j)
            acc[i][j] = (f32x4){0.f, 0.f, 0.f, 0.f};

    for (int ks = 0; ks < 8; ++ks) {
        const int k0 = ks << 5;
        short8 af[4];
        for (int i = 0; i < 4; ++i)
            af[i] = *(const short8*)(Hl + (wv + i * 16 + m15) * 264 + k0 + kq * 8);

        const float xb = X0 + GH * (float)(k0 + kq * 8);
        float xk[8];
        #pragma unroll
        for (int j = 0; j < 8; ++j) xk[j] = xb + GH * (float)j;

        short8 bfr[4];
        #pragma unroll
        for (int ni = 0; ni < 4; ++ni) {
            float w[8];
            #pragma unroll
            for (int j = 0; j < 8; ++j) {
                float d = q[ni] - xk[j];
                w[j] = exp2f(c2 * d * d);
            }
            union U { short8 s; uint4 u; } e;
            e.u = cvt8u(make_float4(w[0], w[1], w[2], w[3]),
                        make_float4(w[4], w[5], w[6], w[7]));
            bfr[ni] = e.s;
        }
        for (int mi = 0; mi < 4; ++mi)
            for (int ni = 0; ni < 4; ++ni)
                acc[mi][ni] = __builtin_amdgcn_mfma_f32_16x16x32_bf16(
                    af[mi], bfr[ni], acc[mi][ni], 0, 0, 0);
    }

    for (int mi = 0; mi < 4; ++mi)
        for (int ni = 0; ni < 4; ++ni) {
            int t = t0 + wt + ni * 16 + m15;
            float* o = out + (size_t)(b * 4096 + t) * 512
                           + v0 + wv + mi * 16 + (kq << 2);
            *(f32x4*)o = acc[mi][ni];
        }
}

extern "C" void kernel_launch(void* const* d_in, const int* in_sizes, int n_in,
                              void* d_out, int out_size, void* d_ws, size_t ws_size,
                              hipStream_t stream)
{
    const float* query = (const float*)d_in[0];   // [4,4096,1]
    const float* key   = (const float*)d_in[1];   // [4,4096,1]
    const float* value = (const float*)d_in[2];   // [4,512,4096]
    const float* lsc   = (const float*)d_in[3];   // scalar
    float* out = (float*)d_out;                   // [4,4096,512]

    float* Hpart = (float*)d_ws;                                   // 16 MB
    u16*   Hbf   = (u16*)((char*)d_ws + (size_t)16 * 1024 * 1024); // 1 MB

    hpart_kernel<<<dim3(16, 4, 8), 256, 0, stream>>>(key, value, Hpart);
    hred_kernel<<<256, 256, 0, stream>>>(Hpart, Hbf);
    gemm_kernel<<<dim3(4, 32, 4), 256, 128 * 264 * 2, stream>>>(query, lsc, Hbf, out);
}

// Round 3
// 118.576 us; speedup vs baseline: 1.1230x; 1.1219x over previous
//
#include <hip/hip_runtime.h>

typedef unsigned short u16;
typedef __attribute__((ext_vector_type(8))) short short8;
typedef __attribute__((ext_vector_type(4))) float f32x4;

#define X0    (-6.0f)
#define GH    (12.0f / 256.0f)     // grid spacing h = 0.046875
#define LOG2E 1.44269504089f

// gfx950 hardware packed f32->bf16 (RNE), no builtin -- inline asm per guide T12.
__device__ __forceinline__ unsigned int cvtpk(float lo, float hi) {
    unsigned int r;
    asm("v_cvt_pk_bf16_f32 %0, %1, %2" : "=v"(r) : "v"(lo), "v"(hi));
    return r;
}
__device__ __forceinline__ uint4 cvt8u(float4 lo, float4 hi) {
    return make_uint4(cvtpk(lo.x, lo.y), cvtpk(lo.z, lo.w),
                      cvtpk(hi.x, hi.y), cvtpk(hi.z, hi.w));
}
__device__ __forceinline__ u16 f2bf(float x) {   // single value via HW RNE
    return (u16)(cvtpk(x, x) & 0xffffu);
}
__device__ __forceinline__ float bf2f_lo(unsigned int u) {
    union { unsigned int x; float f; } v; v.x = u << 16; return v.f;
}
__device__ __forceinline__ float bf2f_hi(unsigned int u) {
    union { unsigned int x; float f; } v; v.x = u & 0xffff0000u; return v.f;
}
__device__ __forceinline__ void glds16(const float* g, const float* l) {
    __builtin_amdgcn_global_load_lds(
        (const __attribute__((address_space(1))) void*)g,
        (__attribute__((address_space(3))) void*)l, 16, 0, 0);
}

// K1: Hpart[b][ks][v][j] = bf16( sum_{s in chunk} value[v][s] * W_cic[s][j] ).
// M=32 v-rows/block, N=256 j, K-chunk=512 s. Full 64 KB A-tile prefetched
// (16 glds16 in flight, ONE barrier). CIC weight built as tent function:
//   w = max(0, 1 - |J - (j+f)|)   == (j==J)?1-f : (j+1==J)?f : 0
// (3 VALU per (s,J) incl. free |x| modifier, vs 5 for the select chain).
__global__ __launch_bounds__(256) void hpart_kernel(
    const float* __restrict__ key, const float* __restrict__ value,
    u16* __restrict__ Hpart)
{
    __shared__ float Vt[16 * 1024];   // 64 KB, [kk][row][32 f32], chunk-swizzled
    __shared__ float tl[512];         // t = (float)j + f

    const int tid   = threadIdx.x;
    const int v0    = blockIdx.x << 5;    // 0..480
    const int b     = blockIdx.y;
    const int ks    = blockIdx.z;
    const int kbase = ks << 9;            // 512-wide s chunk
    const int lane  = tid & 63;
    const int wave  = tid >> 6;
    const int wj    = wave << 6;          // wave owns 64 j
    const int m15   = lane & 15;
    const int kq    = lane >> 4;

    #pragma unroll
    for (int r = 0; r < 2; ++r) {
        int s = tid + (r << 8);
        float k = key[b * 4096 + kbase + s];
        float u = (k - X0) * (256.0f / 12.0f);
        int j = (int)floorf(u);
        j = j < 0 ? 0 : (j > 254 ? 254 : j);
        float f = u - (float)j;
        f = f < 0.0f ? 0.0f : (f > 1.0f ? 1.0f : f);
        tl[s] = (float)j + f;
    }

    // issue ALL 16 tile-loads (16B swizzle on the global source, LDS linear)
    const int srow = tid >> 3;                   // 0..31
    const int scs  = (tid & 7) ^ (srow & 7);     // swizzled 16B chunk
    const float* gsrc = value + (size_t)(b * 512 + v0 + srow) * 4096 + kbase
                              + (scs << 2);
    const float* ldst = Vt + (srow << 5) + ((tid & 7) << 2);
    #pragma unroll
    for (int kk = 0; kk < 16; ++kk)
        glds16(gsrc + (kk << 5), ldst + (kk << 10));

    f32x4 acc[2][4];
    #pragma unroll
    for (int i = 0; i < 2; ++i)
        #pragma unroll
        for (int j = 0; j < 4; ++j)
            acc[i][j] = (f32x4){0.f, 0.f, 0.f, 0.f};

    __syncthreads();     // drains all 16 glds + LUT writes; only barrier in K1

    for (int kk = 0; kk < 16; ++kk) {
        const float* Vk = Vt + (kk << 10);

        union U { short8 s; uint4 u; } af[2];
        #pragma unroll
        for (int mi = 0; mi < 2; ++mi) {
            int m  = mi * 16 + m15;
            int c0 = ((2 * kq)     ^ (m & 7)) << 2;
            int c1 = ((2 * kq + 1) ^ (m & 7)) << 2;
            float4 lo = *(const float4*)(Vk + (m << 5) + c0);
            float4 hi = *(const float4*)(Vk + (m << 5) + c1);
            af[mi].u = cvt8u(lo, hi);
        }

        float ts[8];
        #pragma unroll
        for (int i = 0; i < 8; ++i)
            ts[i] = tl[(kk << 5) + (kq << 3) + i];

        #pragma unroll
        for (int ni = 0; ni < 4; ++ni) {
            const float J = (float)(wj + ni * 16 + m15);
            float w[8];
            #pragma unroll
            for (int i = 0; i < 8; ++i) {
                float d = 1.0f - fabsf(J - ts[i]);
                w[i] = d > 0.0f ? d : 0.0f;
            }
            union U bf;
            bf.u = cvt8u(make_float4(w[0], w[1], w[2], w[3]),
                         make_float4(w[4], w[5], w[6], w[7]));
            #pragma unroll
            for (int mi = 0; mi < 2; ++mi)
                acc[mi][ni] = __builtin_amdgcn_mfma_f32_16x16x32_bf16(
                    af[mi].s, bf.s, acc[mi][ni], 0, 0, 0);
        }
    }

    // private-plane epilogue: bf16 scalar stores, no atomics
    #pragma unroll
    for (int mi = 0; mi < 2; ++mi)
        #pragma unroll
        for (int ni = 0; ni < 4; ++ni) {
            #pragma unroll
            for (int r = 0; r < 4; ++r) {
                int v = v0 + mi * 16 + (kq << 2) + r;      // row = quad*4+reg
                Hpart[((size_t)(b * 8 + ks) * 512 + v) * 256
                      + wj + ni * 16 + m15] = f2bf(acc[mi][ni][r]);
            }
        }
}

// K2: Hbf[b][v][j] = bf16( sum_{ks<8} Hpart[b][ks][v][j] ). Streaming, 9 MB.
__global__ __launch_bounds__(256) void hred_kernel(
    const u16* __restrict__ Hpart, u16* __restrict__ Hbf)
{
    const int gid  = blockIdx.x * 256 + threadIdx.x;   // 0..65535
    const int b    = gid >> 14;
    const size_t off8 = (size_t)(gid & 16383) * 8;     // 8 u16 per thread
    float s[8];
    #pragma unroll
    for (int i = 0; i < 8; ++i) s[i] = 0.f;
    #pragma unroll
    for (int ks = 0; ks < 8; ++ks) {
        const u16* p = Hpart + (size_t)(b * 8 + ks) * 131072 + off8;
        uint4 a = *(const uint4*)p;                    // 8 bf16
        s[0] += bf2f_lo(a.x); s[1] += bf2f_hi(a.x);
        s[2] += bf2f_lo(a.y); s[3] += bf2f_hi(a.y);
        s[4] += bf2f_lo(a.z); s[5] += bf2f_hi(a.z);
        s[6] += bf2f_lo(a.w); s[7] += bf2f_hi(a.w);
    }
    *(uint4*)(Hbf + (size_t)b * 131072 + off8) =
        cvt8u(make_float4(s[0], s[1], s[2], s[3]),
              make_float4(s[4], s[5], s[6], s[7]));
}

// K3: out[b][t][v] = sum_k G(q_t, x_k) * H[v][k].
// Whole H-tile (128 v x 256 k bf16) staged ONCE -> single barrier, then
// 8 barrier-free MFMA steps. Gaussian row built INCREMENTALLY:
//   e_{j+1} = e_j * r_j,  r_{j+1} = r_j * rho,  rho = 2^(2*c2*h^2)
// -> 2 exp2 + 14 mul per (ks,ni) instead of 8 exp2 + 24 VALU.
__global__ __launch_bounds__(256) void gemm_kernel(
    const float* __restrict__ query, const float* __restrict__ log_scale,
    const u16* __restrict__ Hbf, float* __restrict__ out)
{
    extern __shared__ u16 Hl[];        // 128 rows x 264 stride = 67584 B

    const int tid  = threadIdx.x;
    const int v0   = blockIdx.x << 7;
    const int t0   = blockIdx.y << 7;
    const int b    = blockIdx.z;
    const int lane = tid & 63;
    const int wave = tid >> 6;
    const int wv   = (wave & 1) << 6;
    const int wt   = (wave >> 1) << 6;
    const int m15  = lane & 15;
    const int kq   = lane >> 4;

    const float c2   = -0.5f * LOG2E * exp2f(-2.0f * LOG2E * log_scale[0]);
    const float rho  = exp2f(2.0f * c2 * GH * GH);   // ratio-of-ratios
    const float c2h2 = c2 * GH * GH;
    const float A    = 2.0f * c2 * GH;

    float q[4];
    for (int ni = 0; ni < 4; ++ni)
        q[ni] = query[b * 4096 + t0 + wt + ni * 16 + m15];

    // stage: thread = (row = tid>>1, half = tid&1); contiguous 256 B per thread
    {
        const int row = tid >> 1, half = tid & 1;
        const u16* src = Hbf + (size_t)(b * 512 + v0 + row) * 256 + half * 128;
        u16* dst = Hl + row * 264 + half * 128;
        #pragma unroll
        for (int i = 0; i < 16; ++i)
            *(uint4*)(dst + i * 8) = *(const uint4*)(src + i * 8);
    }
    __syncthreads();

    f32x4 acc[4][4];
    for (int i = 0; i < 4; ++i)
        for (int j = 0; j < 4; ++j)
            acc[i][j] = (f32x4){0.f, 0.f, 0.f, 0.f};

    for (int ks = 0; ks < 8; ++ks) {
        const int k0 = ks << 5;
        short8 af[4];
        for (int i = 0; i < 4; ++i)
            af[i] = *(const short8*)(Hl + (wv + i * 16 + m15) * 264 + k0 + kq * 8);

        const float xb = X0 + GH * (float)(k0 + kq * 8);

        short8 bfr[4];
        #pragma unroll
        for (int ni = 0; ni < 4; ++ni) {
            float d0 = q[ni] - xb;
            float e  = exp2f(c2 * d0 * d0);        // w at j=0
            float r  = exp2f(c2h2 - A * d0);       // e_{j+1}/e_j at j=0
            float w[8];
            #pragma unroll
            for (int j = 0; j < 8; ++j) {
                w[j] = e;
                e *= r;
                r *= rho;
            }
            union U { short8 s; uint4 u; } v;
            v.u = cvt8u(make_float4(w[0], w[1], w[2], w[3]),
                        make_float4(w[4], w[5], w[6], w[7]));
            bfr[ni] = v.s;
        }
        for (int mi = 0; mi < 4; ++mi)
            for (int ni = 0; ni < 4; ++ni)
                acc[mi][ni] = __builtin_amdgcn_mfma_f32_16x16x32_bf16(
                    af[mi], bfr[ni], acc[mi][ni], 0, 0, 0);
    }

    for (int mi = 0; mi < 4; ++mi)
        for (int ni = 0; ni < 4; ++ni) {
            int t = t0 + wt + ni * 16 + m15;
            float* o = out + (size_t)(b * 4096 + t) * 512
                           + v0 + wv + mi * 16 + (kq << 2);
            *(f32x4*)o = acc[mi][ni];
        }
}

extern "C" void kernel_launch(void* const* d_in, const int* in_sizes, int n_in,
                              void* d_out, int out_size, void* d_ws, size_t ws_size,
                              hipStream_t stream)
{
    const float* query = (const float*)d_in[0];   // [4,4096,1]
    const float* key   = (const float*)d_in[1];   // [4,4096,1]
    const float* value = (const float*)d_in[2];   // [4,512,4096]
    const float* lsc   = (const float*)d_in[3];   // scalar
    float* out = (float*)d_out;                   // [4,4096,512]

    u16* Hpart = (u16*)d_ws;                                      // 8 MB (bf16)
    u16* Hbf   = (u16*)((char*)d_ws + (size_t)8 * 1024 * 1024);   // 1 MB

    hpart_kernel<<<dim3(16, 4, 8), 256, 0, stream>>>(key, value, Hpart);
    hred_kernel<<<256, 256, 0, stream>>>(Hpart, Hbf);
    gemm_kernel<<<dim3(4, 32, 4), 256, 128 * 264 * 2, stream>>>(query, lsc, Hbf, out);
}